// Round 4
// baseline (414.853 us; speedup 1.0000x reference)
//
#include <hip/hip_runtime.h>
#include <math.h>

// Bahdanau attention, round 3: counted-vmcnt pipelined energy GEMM (T4).
//   B=64, S=4096, H=512, all fp32 in/out.
//   ws: dp (B*H f32) | W2t (H*H bf16, K-step-tiled + XOR-swizzled) | pctx = 2.625 MiB
//   energy lives in d_out's attn region; softmax in place.

#define BATCH 64
#define SEQ   4096
#define HID   512

typedef __attribute__((ext_vector_type(8))) short bf16x8;
typedef __attribute__((ext_vector_type(4))) float f32x4;

__device__ __forceinline__ float fast_tanh(float x) {
    return 1.0f - 2.0f / (__expf(2.0f * x) + 1.0f);
}

__device__ __forceinline__ unsigned cvt2(float lo, float hi) {
    unsigned r;
    asm("v_cvt_pk_bf16_f32 %0, %1, %2" : "=v"(r) : "v"(lo), "v"(hi));
    return r;
}

__device__ __forceinline__ void gload_lds16(const void* g, void* l) {
    __builtin_amdgcn_global_load_lds(
        (const __attribute__((address_space(1))) unsigned*)g,
        (__attribute__((address_space(3))) unsigned*)l, 16, 0, 0);
}

// ---------------------------------------------------------------------------
// K0: W2 fp32 -> bf16, K-step-tiled fragment order, XOR swizzle pre-applied.
// Per K-step kb (BK=32): 16B slot f = g*4 + rg holds W2[g][kb*32+rg*8..+7],
// stored at slot f ^ ((f>>3)&7).
// ---------------------------------------------------------------------------
__global__ void k_cvtW2(const float* __restrict__ W2, ushort* __restrict__ W2t)
{
    const int n  = blockIdx.x * 256 + threadIdx.x;
    const int kb = n >> 11;
    const int f  = n & 2047;
    const int g  = f >> 2, rg = f & 3;
    const float* src = W2 + (size_t)g * HID + kb * 32 + rg * 8;
    const float4 x = *reinterpret_cast<const float4*>(src);
    const float4 y = *reinterpret_cast<const float4*>(src + 4);
    uint4 u;
    u.x = cvt2(x.x, x.y);  u.y = cvt2(x.z, x.w);
    u.z = cvt2(y.x, y.y);  u.w = cvt2(y.z, y.w);
    const int slot = f ^ ((f >> 3) & 7);
    *reinterpret_cast<uint4*>(W2t + (size_t)kb * 16384 + slot * 8) = u;
}

// ---------------------------------------------------------------------------
// K1: dp[b][g] = sum_h dh[b][h] * W1[g][h]  (fp32, tiny)
// ---------------------------------------------------------------------------
__global__ void k_decproj(const float* __restrict__ dh,
                          const float* __restrict__ W1,
                          float* __restrict__ dp)
{
    __shared__ float wrow[HID];
    const int g = blockIdx.x;
    const int t = threadIdx.x;
    for (int i = t; i < HID; i += 256) wrow[i] = W1[g * HID + i];
    __syncthreads();

    const int b = t >> 2, q = t & 3;
    const float* dhb = dh + b * HID + q * 128;
    const float* wr  = wrow + q * 128;
    float acc = 0.f;
    #pragma unroll 8
    for (int i = 0; i < 128; i += 4) {
        const float4 d4 = *reinterpret_cast<const float4*>(dhb + i);
        acc = fmaf(d4.x, wr[i + 0], acc);
        acc = fmaf(d4.y, wr[i + 1], acc);
        acc = fmaf(d4.z, wr[i + 2], acc);
        acc = fmaf(d4.w, wr[i + 3], acc);
    }
    acc += __shfl_xor(acc, 1);
    acc += __shfl_xor(acc, 2);
    if (q == 0) dp[b * HID + g] = acc;
}

// ---------------------------------------------------------------------------
// K2: energy GEMM, counted-vmcnt pipeline.
// grid = (32 s-chunks, 64 b), 512 thr (8 waves as 2M x 4N).
// Block tile 128s x 512g, BK=32, 16 K-steps fully unrolled.
// Steady-state in-flight entering step kb: {aload(kb):2, glds(kb):4,
// aload(kb+1):2} -> s_waitcnt vmcnt(2) drains stage(kb) only.
// ---------------------------------------------------------------------------
#define LDA 40

__global__ __launch_bounds__(512, 2)
void k_energy(const float* __restrict__ enc, const ushort* __restrict__ W2t,
              const float* __restrict__ dp,  const float* __restrict__ v,
              float* __restrict__ energy)
{
    __shared__ __align__(16) ushort As[128 * LDA];     // 10 KiB
    __shared__ __align__(16) ushort Bs[2][16384];      // 2 x 32 KiB
    __shared__ float part[8][64];                      //  2 KiB

    const int b    = blockIdx.y;
    const int s0   = blockIdx.x * 128;
    const int t    = threadIdx.x;
    const int lane = t & 63;
    const int wv   = t >> 6;
    const int wm   = wv >> 2, wn = wv & 3;
    const int gl   = lane & 15, rg = lane >> 4;

    f32x4 acc[4][8];
    const f32x4 z = {0.f, 0.f, 0.f, 0.f};
    #pragma unroll
    for (int m = 0; m < 4; ++m)
        #pragma unroll
        for (int n = 0; n < 8; ++n) acc[m][n] = z;

    const int arow = t >> 2, akq = t & 3;
    const float* aptr = enc + ((size_t)(s0 + arow) * BATCH + b) * HID + akq * 8;

    int aoff[4];
    #pragma unroll
    for (int m = 0; m < 4; ++m)
        aoff[m] = (wm * 64 + m * 16 + gl) * LDA + rg * 8;
    int boff[8];
    #pragma unroll
    for (int n = 0; n < 8; ++n) {
        const int g = wn * 128 + n * 16 + gl;
        const int f = g * 4 + rg;
        boff[n] = (f ^ ((f >> 3) & 7)) * 8;
    }

    const char* wsrc = (const char*)W2t;
    float4 ar[3][2];

    // prologue: aload(0); glds(0); aload(1)   (oldest-first drain order)
    ar[0][0] = *reinterpret_cast<const float4*>(aptr);
    ar[0][1] = *reinterpret_cast<const float4*>(aptr + 4);
    #pragma unroll
    for (int r = 0; r < 4; ++r)
        gload_lds16(wsrc + (r * 512 + t) * 16,
                    (char*)&Bs[0][0] + (r * 512 + t) * 16);
    ar[1][0] = *reinterpret_cast<const float4*>(aptr + 32);
    ar[1][1] = *reinterpret_cast<const float4*>(aptr + 36);

    #pragma unroll
    for (int kb = 0; kb < 16; ++kb) {
        // BARRIER1: drain stage(kb), keep aload(kb+1) flying
        if (kb < 15) asm volatile("s_waitcnt vmcnt(2)" ::: "memory");
        else         asm volatile("s_waitcnt vmcnt(0)" ::: "memory");
        __builtin_amdgcn_s_barrier();

        // write As(kb) from regs; read B fragments (Bs[kb&1] is ready)
        {
            uint4 aw;
            const float4 a0 = ar[kb % 3][0], a1 = ar[kb % 3][1];
            aw.x = cvt2(a0.x, a0.y);  aw.y = cvt2(a0.z, a0.w);
            aw.z = cvt2(a1.x, a1.y);  aw.w = cvt2(a1.z, a1.w);
            *reinterpret_cast<uint4*>(&As[arow * LDA + akq * 8]) = aw;
        }
        bf16x8 bf[8];
        #pragma unroll
        for (int n = 0; n < 8; ++n)
            bf[n] = *reinterpret_cast<const bf16x8*>(&Bs[kb & 1][boff[n]]);

        asm volatile("s_waitcnt lgkmcnt(0)" ::: "memory");
        __builtin_amdgcn_s_barrier();

        bf16x8 af[4];
        #pragma unroll
        for (int m = 0; m < 4; ++m)
            af[m] = *reinterpret_cast<const bf16x8*>(&As[aoff[m]]);

        // issue next stages; they fly across the MFMA block and next barrier
        if (kb < 15) {
            const char* src = wsrc + (size_t)(kb + 1) * 32768;
            #pragma unroll
            for (int r = 0; r < 4; ++r)
                gload_lds16(src + (r * 512 + t) * 16,
                            (char*)&Bs[(kb + 1) & 1][0] + (r * 512 + t) * 16);
        }
        if (kb < 14) {
            ar[(kb + 2) % 3][0] = *reinterpret_cast<const float4*>(aptr + (kb + 2) * 32);
            ar[(kb + 2) % 3][1] = *reinterpret_cast<const float4*>(aptr + (kb + 2) * 32 + 4);
        }

        #pragma unroll
        for (int m = 0; m < 4; ++m)
            #pragma unroll
            for (int n = 0; n < 8; ++n)
                acc[m][n] = __builtin_amdgcn_mfma_f32_16x16x32_bf16(
                    af[m], bf[n], acc[m][n], 0, 0, 0);
    }

    // epilogue: sum over this lane's g of tanh(dp+c)*v
    float dpv[8], vv[8];
    #pragma unroll
    for (int n = 0; n < 8; ++n) {
        const int g = wn * 128 + n * 16 + gl;
        dpv[n] = dp[b * HID + g];
        vv[n]  = v[g];
    }
    float p[4][4];
    #pragma unroll
    for (int m = 0; m < 4; ++m)
        #pragma unroll
        for (int r = 0; r < 4; ++r) p[m][r] = 0.f;
    #pragma unroll
    for (int n = 0; n < 8; ++n)
        #pragma unroll
        for (int m = 0; m < 4; ++m)
            #pragma unroll
            for (int r = 0; r < 4; ++r)
                p[m][r] += fast_tanh(dpv[n] + acc[m][n][r]) * vv[n];

    #pragma unroll
    for (int m = 0; m < 4; ++m)
        #pragma unroll
        for (int r = 0; r < 4; ++r) {
            float x = p[m][r];
            x += __shfl_xor(x, 1);
            x += __shfl_xor(x, 2);
            x += __shfl_xor(x, 4);
            x += __shfl_xor(x, 8);
            p[m][r] = x;
        }
    if (gl == 0) {
        #pragma unroll
        for (int m = 0; m < 4; ++m)
            #pragma unroll
            for (int r = 0; r < 4; ++r)
                part[wv][m * 16 + rg * 4 + r] = p[m][r];
    }
    __syncthreads();

    if (t < 128) {
        const int row = t & 63, wmf = t >> 6;
        const float e = part[wmf * 4 + 0][row] + part[wmf * 4 + 1][row]
                      + part[wmf * 4 + 2][row] + part[wmf * 4 + 3][row];
        energy[(size_t)b * SEQ + s0 + t] = e;
    }
}

// ---------------------------------------------------------------------------
// K3: softmax over s per b, IN PLACE on the attn region of d_out.
// ---------------------------------------------------------------------------
__global__ void k_softmax(float* __restrict__ attn)
{
    __shared__ float redm[4], reds[4];
    const int b = blockIdx.x, t = threadIdx.x;
    float* e = attn + (size_t)b * SEQ;

    float4 ev[4];
    float m = -3.4e38f;
    #pragma unroll
    for (int i = 0; i < 4; ++i) {
        ev[i] = *reinterpret_cast<const float4*>(e + i * 1024 + t * 4);
        m = fmaxf(m, fmaxf(fmaxf(ev[i].x, ev[i].y), fmaxf(ev[i].z, ev[i].w)));
    }
    #pragma unroll
    for (int off = 1; off < 64; off <<= 1) m = fmaxf(m, __shfl_xor(m, off));
    if ((t & 63) == 0) redm[t >> 6] = m;
    __syncthreads();
    m = fmaxf(fmaxf(redm[0], redm[1]), fmaxf(redm[2], redm[3]));

    float s = 0.f;
    #pragma unroll
    for (int i = 0; i < 4; ++i) {
        ev[i].x = __expf(ev[i].x - m);  ev[i].y = __expf(ev[i].y - m);
        ev[i].z = __expf(ev[i].z - m);  ev[i].w = __expf(ev[i].w - m);
        s += (ev[i].x + ev[i].y) + (ev[i].z + ev[i].w);
    }
    #pragma unroll
    for (int off = 1; off < 64; off <<= 1) s += __shfl_xor(s, off);
    if ((t & 63) == 0) reds[t >> 6] = s;
    __syncthreads();
    s = (reds[0] + reds[1]) + (reds[2] + reds[3]);
    const float inv = 1.0f / s;

    #pragma unroll
    for (int i = 0; i < 4; ++i) {
        const float4 w4 = make_float4(ev[i].x * inv, ev[i].y * inv,
                                      ev[i].z * inv, ev[i].w * inv);
        *reinterpret_cast<float4*>(e + i * 1024 + t * 4) = w4;
    }
}

// ---------------------------------------------------------------------------
// K4: partial context. grid = (64 b, 16 s-splits), 256 threads.
// ---------------------------------------------------------------------------
__global__ void k_ctxpart(const float* __restrict__ enc,
                          const float* __restrict__ attn,
                          float* __restrict__ pctx)
{
    __shared__ float w[256];
    const int b  = blockIdx.x;
    const int sp = blockIdx.y;
    const int t  = threadIdx.x;

    w[t] = attn[(size_t)b * SEQ + sp * 256 + t];
    __syncthreads();

    const float2* e2 = reinterpret_cast<const float2*>(enc);
    size_t idx = ((size_t)sp * 256 * BATCH + b) * (HID / 2) + t;
    const size_t stride = (size_t)BATCH * (HID / 2);

    float ax = 0.f, ay = 0.f;
    #pragma unroll 4
    for (int s = 0; s < 256; ++s) {
        const float2 ev = e2[idx];
        const float ws = w[s];
        ax = fmaf(ws, ev.x, ax);
        ay = fmaf(ws, ev.y, ay);
        idx += stride;
    }
    float2* p2 = reinterpret_cast<float2*>(pctx);
    p2[((size_t)sp * BATCH + b) * (HID / 2) + t] = make_float2(ax, ay);
}

// ---------------------------------------------------------------------------
// K5: context[b][h] = sum over 16 splits.
// ---------------------------------------------------------------------------
__global__ void k_ctxsum(const float* __restrict__ pctx,
                         float* __restrict__ ctx)
{
    const int i = blockIdx.x * 256 + threadIdx.x;
    float s = 0.f;
    #pragma unroll
    for (int sp = 0; sp < 16; ++sp) s += pctx[(size_t)sp * BATCH * HID + i];
    ctx[i] = s;
}

// ---------------------------------------------------------------------------
extern "C" void kernel_launch(void* const* d_in, const int* in_sizes, int n_in,
                              void* d_out, int out_size, void* d_ws, size_t ws_size,
                              hipStream_t stream)
{
    const float* dh  = (const float*)d_in[0];
    const float* enc = (const float*)d_in[1];
    const float* W1  = (const float*)d_in[2];
    const float* W2  = (const float*)d_in[3];
    const float* v   = (const float*)d_in[4];

    float* out  = (float*)d_out;
    float* ctx  = out;                           // 64*512
    float* attn = out + BATCH * HID;             // 64*4096

    float*  dp   = (float*)d_ws;                 // 128 KiB
    ushort* W2t  = (ushort*)(dp + BATCH * HID);  // 512 KiB
    float*  pctx = (float*)(W2t + HID * HID);    // 2 MiB

    k_cvtW2  <<<128, 256, 0, stream>>>(W2, W2t);
    k_decproj<<<HID, 256, 0, stream>>>(dh, W1, dp);
    k_energy <<<dim3(SEQ / 128, BATCH), 512, 0, stream>>>(enc, W2t, dp, v, attn);
    k_softmax<<<BATCH, 256, 0, stream>>>(attn);
    k_ctxpart<<<dim3(BATCH, 16), 256, 0, stream>>>(enc, attn, pctx);
    k_ctxsum <<<BATCH * HID / 256, 256, 0, stream>>>(pctx, ctx);
}

// Round 5
// 371.068 us; speedup vs baseline: 1.1180x; 1.1180x over previous
//
#include <hip/hip_runtime.h>
#include <math.h>

// Bahdanau attention, round 4: occupancy-first energy GEMM.
// 256-thr blocks, tile 64s x 256g, 4 waves (1M x 4N), acc 4x4 -> ~120 regs
// -> 3-4 independent blocks/CU (TLP hides barrier drains, m114/m97 mechanism).
// Two g-halves write eparts[2][b][s]; k_softmax sums them.
//   ws: dp | W2t | shared2 (eparts during energy/softmax, pctx after) = 2.625 MiB

#define BATCH 64
#define SEQ   4096
#define HID   512

typedef __attribute__((ext_vector_type(8))) short bf16x8;
typedef __attribute__((ext_vector_type(4))) float f32x4;

__device__ __forceinline__ float fast_tanh(float x) {
    return 1.0f - 2.0f / (__expf(2.0f * x) + 1.0f);
}

__device__ __forceinline__ unsigned cvt2(float lo, float hi) {
    unsigned r;
    asm("v_cvt_pk_bf16_f32 %0, %1, %2" : "=v"(r) : "v"(lo), "v"(hi));
    return r;
}

__device__ __forceinline__ void gload_lds16(const void* g, void* l) {
    __builtin_amdgcn_global_load_lds(
        (const __attribute__((address_space(1))) unsigned*)g,
        (__attribute__((address_space(3))) unsigned*)l, 16, 0, 0);
}

// ---------------------------------------------------------------------------
// K0: W2 fp32 -> bf16, K-step-tiled fragment order, XOR swizzle pre-applied.
// Per K-step kb (BK=32): 16B slot f = g*4 + rg holds W2[g][kb*32+rg*8..+7],
// stored at slot f ^ ((f>>3)&7)  (bijective; self-contained per 1024-slot
// g-half since the XOR bits come from f>>3 within the half).
// ---------------------------------------------------------------------------
__global__ void k_cvtW2(const float* __restrict__ W2, ushort* __restrict__ W2t)
{
    const int n  = blockIdx.x * 256 + threadIdx.x;
    const int kb = n >> 11;
    const int f  = n & 2047;
    const int g  = f >> 2, rg = f & 3;
    const float* src = W2 + (size_t)g * HID + kb * 32 + rg * 8;
    const float4 x = *reinterpret_cast<const float4*>(src);
    const float4 y = *reinterpret_cast<const float4*>(src + 4);
    uint4 u;
    u.x = cvt2(x.x, x.y);  u.y = cvt2(x.z, x.w);
    u.z = cvt2(y.x, y.y);  u.w = cvt2(y.z, y.w);
    const int slot = f ^ ((f >> 3) & 7);
    *reinterpret_cast<uint4*>(W2t + (size_t)kb * 16384 + slot * 8) = u;
}

// ---------------------------------------------------------------------------
// K1: dp[b][g] = sum_h dh[b][h] * W1[g][h]  (fp32, tiny)
// ---------------------------------------------------------------------------
__global__ void k_decproj(const float* __restrict__ dh,
                          const float* __restrict__ W1,
                          float* __restrict__ dp)
{
    __shared__ float wrow[HID];
    const int g = blockIdx.x;
    const int t = threadIdx.x;
    for (int i = t; i < HID; i += 256) wrow[i] = W1[g * HID + i];
    __syncthreads();

    const int b = t >> 2, q = t & 3;
    const float* dhb = dh + b * HID + q * 128;
    const float* wr  = wrow + q * 128;
    float acc = 0.f;
    #pragma unroll 8
    for (int i = 0; i < 128; i += 4) {
        const float4 d4 = *reinterpret_cast<const float4*>(dhb + i);
        acc = fmaf(d4.x, wr[i + 0], acc);
        acc = fmaf(d4.y, wr[i + 1], acc);
        acc = fmaf(d4.z, wr[i + 2], acc);
        acc = fmaf(d4.w, wr[i + 3], acc);
    }
    acc += __shfl_xor(acc, 1);
    acc += __shfl_xor(acc, 2);
    if (q == 0) dp[b * HID + g] = acc;
}

// ---------------------------------------------------------------------------
// K2: energy partial GEMM. grid = 8192 linear blocks, 256 thr (4 waves).
// Block decode pairs the two g-halves of one (s-chunk, b) at blockIdx
// distance 8 -> same XCD (round-robin) -> sibling enc reads hit that L2.
// Block tile 64s x 256g, BK=32, 16 K-steps. Wave wv: g_local in [wv*64, +64).
// A: reg-prefetch + cvt_pk -> As (LDA=40 pad, 2-way max).
// B: glds from pre-swizzled W2t, double-buffered.
// ---------------------------------------------------------------------------
#define LDA 40

__global__ __launch_bounds__(256, 3)
void k_energy(const float* __restrict__ enc, const ushort* __restrict__ W2t,
              const float* __restrict__ dp,  const float* __restrict__ v,
              float* __restrict__ eparts)
{
    __shared__ __align__(16) ushort As[64 * LDA];      //  5 KiB
    __shared__ __align__(16) ushort Bs[2][8192];       // 2 x 16 KiB
    __shared__ float part[4][64];                      //  1 KiB

    // block decode: idx -> (gh, schunk, b); siblings (gh=0/1) 8 apart.
    const int idx  = blockIdx.x;
    const int g16  = idx >> 4, rr = idx & 15;
    const int gh   = rr >> 3;
    const int pair = (g16 << 3) | (rr & 7);    // 0..4095
    const int schunk = pair & 63;
    const int b      = pair >> 6;
    const int s0     = schunk * 64;

    const int t    = threadIdx.x;
    const int lane = t & 63;
    const int wv   = t >> 6;                   // wave = N-block 0..3
    const int gl   = lane & 15, rg = lane >> 4;

    f32x4 acc[4][4];
    const f32x4 z = {0.f, 0.f, 0.f, 0.f};
    #pragma unroll
    for (int m = 0; m < 4; ++m)
        #pragma unroll
        for (int n = 0; n < 4; ++n) acc[m][n] = z;

    // A staging: thread -> (row = t>>2 in [0,64), kq = t&3), 8 floats/step
    const int arow = t >> 2, akq = t & 3;
    const float* aptr = enc + ((size_t)(s0 + arow) * BATCH + b) * HID + akq * 8;

    int aoff[4];
    #pragma unroll
    for (int m = 0; m < 4; ++m)
        aoff[m] = (m * 16 + gl) * LDA + rg * 8;
    int boff[4];
    #pragma unroll
    for (int n = 0; n < 4; ++n) {
        const int fl = (wv * 64 + n * 16 + gl) * 4 + rg;   // local slot
        boff[n] = (fl ^ ((fl >> 3) & 7)) * 8;
    }

    // W2t source for this g-half: per-kb stride 32768 B, gh offset 16384 B
    const char* wsrc = (const char*)W2t + gh * 16384;

    // prologue: glds B(0); aload(0)
    #pragma unroll
    for (int q = 0; q < 4; ++q)
        gload_lds16(wsrc + (q * 256 + t) * 16,
                    (char*)&Bs[0][0] + (q * 256 + t) * 16);
    float4 a0 = *reinterpret_cast<const float4*>(aptr);
    float4 a1 = *reinterpret_cast<const float4*>(aptr + 4);

    #pragma unroll
    for (int kb = 0; kb < 16; ++kb) {
        __syncthreads();                       // drains glds(kb) + aload(kb)
        {
            uint4 aw;
            aw.x = cvt2(a0.x, a0.y);  aw.y = cvt2(a0.z, a0.w);
            aw.z = cvt2(a1.x, a1.y);  aw.w = cvt2(a1.z, a1.w);
            *reinterpret_cast<uint4*>(&As[arow * LDA + akq * 8]) = aw;
        }
        __syncthreads();                       // As(kb) + Bs[kb&1] visible

        if (kb < 15) {                         // next stages fly across MFMA
            const char* src = wsrc + (size_t)(kb + 1) * 32768;
            #pragma unroll
            for (int q = 0; q < 4; ++q)
                gload_lds16(src + (q * 256 + t) * 16,
                            (char*)&Bs[(kb + 1) & 1][0] + (q * 256 + t) * 16);
            a0 = *reinterpret_cast<const float4*>(aptr + (kb + 1) * 32);
            a1 = *reinterpret_cast<const float4*>(aptr + (kb + 1) * 32 + 4);
        }

        bf16x8 af[4], bfr[4];
        #pragma unroll
        for (int m = 0; m < 4; ++m)
            af[m] = *reinterpret_cast<const bf16x8*>(&As[aoff[m]]);
        #pragma unroll
        for (int n = 0; n < 4; ++n)
            bfr[n] = *reinterpret_cast<const bf16x8*>(&Bs[kb & 1][boff[n]]);
        #pragma unroll
        for (int m = 0; m < 4; ++m)
            #pragma unroll
            for (int n = 0; n < 4; ++n)
                acc[m][n] = __builtin_amdgcn_mfma_f32_16x16x32_bf16(
                    af[m], bfr[n], acc[m][n], 0, 0, 0);
    }

    // epilogue: partial energy over this block's 256 g
    float dpv[4], vv[4];
    #pragma unroll
    for (int n = 0; n < 4; ++n) {
        const int g = gh * 256 + wv * 64 + n * 16 + gl;
        dpv[n] = dp[b * HID + g];
        vv[n]  = v[g];
    }
    float p[4][4];
    #pragma unroll
    for (int m = 0; m < 4; ++m)
        #pragma unroll
        for (int r = 0; r < 4; ++r) p[m][r] = 0.f;
    #pragma unroll
    for (int n = 0; n < 4; ++n)
        #pragma unroll
        for (int m = 0; m < 4; ++m)
            #pragma unroll
            for (int r = 0; r < 4; ++r)
                p[m][r] += fast_tanh(dpv[n] + acc[m][n][r]) * vv[n];

    #pragma unroll
    for (int m = 0; m < 4; ++m)
        #pragma unroll
        for (int r = 0; r < 4; ++r) {
            float x = p[m][r];
            x += __shfl_xor(x, 1);
            x += __shfl_xor(x, 2);
            x += __shfl_xor(x, 4);
            x += __shfl_xor(x, 8);
            p[m][r] = x;
        }
    if (gl == 0) {
        #pragma unroll
        for (int m = 0; m < 4; ++m)
            #pragma unroll
            for (int r = 0; r < 4; ++r)
                part[wv][m * 16 + rg * 4 + r] = p[m][r];
    }
    __syncthreads();

    if (t < 64) {
        const float e = part[0][t] + part[1][t] + part[2][t] + part[3][t];
        eparts[(size_t)gh * BATCH * SEQ + (size_t)b * SEQ + s0 + t] = e;
    }
}

// ---------------------------------------------------------------------------
// K3: softmax over s per b; sums the two g-half partials, writes attn.
// ---------------------------------------------------------------------------
__global__ void k_softmax(const float* __restrict__ eparts,
                          float* __restrict__ attn)
{
    __shared__ float redm[4], reds[4];
    const int b = blockIdx.x, t = threadIdx.x;
    const float* e0 = eparts + (size_t)b * SEQ;
    const float* e1 = eparts + (size_t)BATCH * SEQ + (size_t)b * SEQ;

    float4 ev[4];
    float m = -3.4e38f;
    #pragma unroll
    for (int i = 0; i < 4; ++i) {
        const float4 x = *reinterpret_cast<const float4*>(e0 + i * 1024 + t * 4);
        const float4 y = *reinterpret_cast<const float4*>(e1 + i * 1024 + t * 4);
        ev[i] = make_float4(x.x + y.x, x.y + y.y, x.z + y.z, x.w + y.w);
        m = fmaxf(m, fmaxf(fmaxf(ev[i].x, ev[i].y), fmaxf(ev[i].z, ev[i].w)));
    }
    #pragma unroll
    for (int off = 1; off < 64; off <<= 1) m = fmaxf(m, __shfl_xor(m, off));
    if ((t & 63) == 0) redm[t >> 6] = m;
    __syncthreads();
    m = fmaxf(fmaxf(redm[0], redm[1]), fmaxf(redm[2], redm[3]));

    float s = 0.f;
    #pragma unroll
    for (int i = 0; i < 4; ++i) {
        ev[i].x = __expf(ev[i].x - m);  ev[i].y = __expf(ev[i].y - m);
        ev[i].z = __expf(ev[i].z - m);  ev[i].w = __expf(ev[i].w - m);
        s += (ev[i].x + ev[i].y) + (ev[i].z + ev[i].w);
    }
    #pragma unroll
    for (int off = 1; off < 64; off <<= 1) s += __shfl_xor(s, off);
    if ((t & 63) == 0) reds[t >> 6] = s;
    __syncthreads();
    s = (reds[0] + reds[1]) + (reds[2] + reds[3]);
    const float inv = 1.0f / s;

    float* o = attn + (size_t)b * SEQ;
    #pragma unroll
    for (int i = 0; i < 4; ++i) {
        const float4 w4 = make_float4(ev[i].x * inv, ev[i].y * inv,
                                      ev[i].z * inv, ev[i].w * inv);
        *reinterpret_cast<float4*>(o + i * 1024 + t * 4) = w4;
    }
}

// ---------------------------------------------------------------------------
// K4: partial context. grid = (64 b, 16 s-splits), 256 threads.
// ---------------------------------------------------------------------------
__global__ void k_ctxpart(const float* __restrict__ enc,
                          const float* __restrict__ attn,
                          float* __restrict__ pctx)
{
    __shared__ float w[256];
    const int b  = blockIdx.x;
    const int sp = blockIdx.y;
    const int t  = threadIdx.x;

    w[t] = attn[(size_t)b * SEQ + sp * 256 + t];
    __syncthreads();

    const float2* e2 = reinterpret_cast<const float2*>(enc);
    size_t idx = ((size_t)sp * 256 * BATCH + b) * (HID / 2) + t;
    const size_t stride = (size_t)BATCH * (HID / 2);

    float ax = 0.f, ay = 0.f;
    #pragma unroll 4
    for (int s = 0; s < 256; ++s) {
        const float2 ev = e2[idx];
        const float ws = w[s];
        ax = fmaf(ws, ev.x, ax);
        ay = fmaf(ws, ev.y, ay);
        idx += stride;
    }
    float2* p2 = reinterpret_cast<float2*>(pctx);
    p2[((size_t)sp * BATCH + b) * (HID / 2) + t] = make_float2(ax, ay);
}

// ---------------------------------------------------------------------------
// K5: context[b][h] = sum over 16 splits.
// ---------------------------------------------------------------------------
__global__ void k_ctxsum(const float* __restrict__ pctx,
                         float* __restrict__ ctx)
{
    const int i = blockIdx.x * 256 + threadIdx.x;
    float s = 0.f;
    #pragma unroll
    for (int sp = 0; sp < 16; ++sp) s += pctx[(size_t)sp * BATCH * HID + i];
    ctx[i] = s;
}

// ---------------------------------------------------------------------------
extern "C" void kernel_launch(void* const* d_in, const int* in_sizes, int n_in,
                              void* d_out, int out_size, void* d_ws, size_t ws_size,
                              hipStream_t stream)
{
    const float* dh  = (const float*)d_in[0];
    const float* enc = (const float*)d_in[1];
    const float* W1  = (const float*)d_in[2];
    const float* W2  = (const float*)d_in[3];
    const float* v   = (const float*)d_in[4];

    float* out  = (float*)d_out;
    float* ctx  = out;                           // 64*512
    float* attn = out + BATCH * HID;             // 64*4096

    float*  dp      = (float*)d_ws;                  // 128 KiB
    ushort* W2t     = (ushort*)(dp + BATCH * HID);   // 512 KiB
    float*  shared2 = (float*)(W2t + HID * HID);     // 2 MiB, dual-use:
    float*  eparts  = shared2;                       //   [2][B][S] until softmax
    float*  pctx    = shared2;                       //   [16][B][H] after

    k_cvtW2  <<<128, 256, 0, stream>>>(W2, W2t);
    k_decproj<<<HID, 256, 0, stream>>>(dh, W1, dp);
    k_energy <<<8192, 256, 0, stream>>>(enc, W2t, dp, v, eparts);
    k_softmax<<<BATCH, 256, 0, stream>>>(eparts, attn);
    k_ctxpart<<<dim3(BATCH, 16), 256, 0, stream>>>(enc, attn, pctx);
    k_ctxsum <<<BATCH * HID / 256, 256, 0, stream>>>(pctx, ctx);
}

// Round 6
// 341.733 us; speedup vs baseline: 1.2140x; 1.0858x over previous
//
#include <hip/hip_runtime.h>
#include <math.h>

// Bahdanau attention, round 5: occupancy push (4 blocks/CU).
// R4 geometry (64s x 256g, 4 waves, acc 4x4) with a register diet:
// launch_bounds(256,4) + base+imm-offset LDS addressing so each wave fits
// 64 VGPR + 64 AGPR = 128 regs -> 4 waves/SIMD -> 16 waves/CU.
//   ws: dp | W2t | shared2 (eparts then pctx) = 2.625 MiB

#define BATCH 64
#define SEQ   4096
#define HID   512

typedef __attribute__((ext_vector_type(8))) short bf16x8;
typedef __attribute__((ext_vector_type(4))) float f32x4;

__device__ __forceinline__ float fast_tanh(float x) {
    return 1.0f - 2.0f / (__expf(2.0f * x) + 1.0f);
}

__device__ __forceinline__ unsigned cvt2(float lo, float hi) {
    unsigned r;
    asm("v_cvt_pk_bf16_f32 %0, %1, %2" : "=v"(r) : "v"(lo), "v"(hi));
    return r;
}

__device__ __forceinline__ void gload_lds16(const void* g, void* l) {
    __builtin_amdgcn_global_load_lds(
        (const __attribute__((address_space(1))) unsigned*)g,
        (__attribute__((address_space(3))) unsigned*)l, 16, 0, 0);
}

// ---------------------------------------------------------------------------
// K0: W2 fp32 -> bf16, K-step-tiled fragment order, XOR swizzle pre-applied.
// Per K-step kb (BK=32): 16B slot f = g*4 + rg holds W2[g][kb*32+rg*8..+7],
// stored at slot f ^ ((f>>3)&7).
// ---------------------------------------------------------------------------
__global__ void k_cvtW2(const float* __restrict__ W2, ushort* __restrict__ W2t)
{
    const int n  = blockIdx.x * 256 + threadIdx.x;
    const int kb = n >> 11;
    const int f  = n & 2047;
    const int g  = f >> 2, rg = f & 3;
    const float* src = W2 + (size_t)g * HID + kb * 32 + rg * 8;
    const float4 x = *reinterpret_cast<const float4*>(src);
    const float4 y = *reinterpret_cast<const float4*>(src + 4);
    uint4 u;
    u.x = cvt2(x.x, x.y);  u.y = cvt2(x.z, x.w);
    u.z = cvt2(y.x, y.y);  u.w = cvt2(y.z, y.w);
    const int slot = f ^ ((f >> 3) & 7);
    *reinterpret_cast<uint4*>(W2t + (size_t)kb * 16384 + slot * 8) = u;
}

// ---------------------------------------------------------------------------
// K1: dp[b][g] = sum_h dh[b][h] * W1[g][h]  (fp32, tiny)
// ---------------------------------------------------------------------------
__global__ void k_decproj(const float* __restrict__ dh,
                          const float* __restrict__ W1,
                          float* __restrict__ dp)
{
    __shared__ float wrow[HID];
    const int g = blockIdx.x;
    const int t = threadIdx.x;
    for (int i = t; i < HID; i += 256) wrow[i] = W1[g * HID + i];
    __syncthreads();

    const int b = t >> 2, q = t & 3;
    const float* dhb = dh + b * HID + q * 128;
    const float* wr  = wrow + q * 128;
    float acc = 0.f;
    #pragma unroll 8
    for (int i = 0; i < 128; i += 4) {
        const float4 d4 = *reinterpret_cast<const float4*>(dhb + i);
        acc = fmaf(d4.x, wr[i + 0], acc);
        acc = fmaf(d4.y, wr[i + 1], acc);
        acc = fmaf(d4.z, wr[i + 2], acc);
        acc = fmaf(d4.w, wr[i + 3], acc);
    }
    acc += __shfl_xor(acc, 1);
    acc += __shfl_xor(acc, 2);
    if (q == 0) dp[b * HID + g] = acc;
}

// ---------------------------------------------------------------------------
// K2: energy partial GEMM. grid = 8192 linear blocks, 256 thr (4 waves).
// Sibling g-halves of one (s-chunk, b) at blockIdx distance 8 -> same XCD.
// Block tile 64s x 256g, BK=32, 16 K-steps. Wave wv: g_local [wv*64, +64).
// LDS reads via single per-lane base + compile-time offsets:
//   A: abase = gl*40 + rg*8 (u16), frag m at +m*640
//   B: bbase = ((wv*256+gl*4+rg) ^ ((gl>>1)&7)) * 8, frag n at +n*512
//      (XOR term is independent of n/wv: (fl>>3)&7 with fl=wv*256+n*64+gl*4+rg
//       has n*8 ≡ 0 mod 8 -> offsets stay linear in n)
// ---------------------------------------------------------------------------
#define LDA 40

__global__ __launch_bounds__(256, 4)
void k_energy(const float* __restrict__ enc, const ushort* __restrict__ W2t,
              const float* __restrict__ dp,  const float* __restrict__ v,
              float* __restrict__ eparts)
{
    __shared__ __align__(16) ushort As[64 * LDA];      //  5 KiB
    __shared__ __align__(16) ushort Bs[2][8192];       // 2 x 16 KiB
    __shared__ float part[4][64];                      //  1 KiB

    // block decode: idx -> (gh, schunk, b); siblings (gh=0/1) 8 apart.
    const int idx  = blockIdx.x;
    const int g16  = idx >> 4, rr = idx & 15;
    const int gh   = rr >> 3;
    const int pair = (g16 << 3) | (rr & 7);    // 0..4095
    const int schunk = pair & 63;
    const int b      = pair >> 6;
    const int s0     = schunk * 64;

    const int t    = threadIdx.x;
    const int lane = t & 63;
    const int wv   = t >> 6;                   // wave = N-block 0..3
    const int gl   = lane & 15, rg = lane >> 4;

    f32x4 acc[4][4];
    const f32x4 z = {0.f, 0.f, 0.f, 0.f};
    #pragma unroll
    for (int m = 0; m < 4; ++m)
        #pragma unroll
        for (int n = 0; n < 4; ++n) acc[m][n] = z;

    // A staging: thread -> (row = t>>2 in [0,64), kq = t&3), 8 floats/step
    const int arow = t >> 2, akq = t & 3;
    const float* aptr = enc + ((size_t)(s0 + arow) * BATCH + b) * HID + akq * 8;

    // single-base LDS read pointers (offsets fold to ds_read offset:imm)
    const ushort* Ap  = As + gl * LDA + rg * 8;
    const int bbase   = ((wv * 256 + gl * 4 + rg) ^ ((gl >> 1) & 7)) * 8;
    const ushort* Bp0 = &Bs[0][bbase];
    const ushort* Bp1 = &Bs[1][bbase];

    // W2t source for this g-half: per-kb stride 32768 B, gh offset 16384 B
    const char* wsrc = (const char*)W2t + gh * 16384;

    // prologue: glds B(0); aload(0)
    #pragma unroll
    for (int q = 0; q < 4; ++q)
        gload_lds16(wsrc + (q * 256 + t) * 16,
                    (char*)&Bs[0][0] + (q * 256 + t) * 16);
    float4 a0 = *reinterpret_cast<const float4*>(aptr);
    float4 a1 = *reinterpret_cast<const float4*>(aptr + 4);

    #pragma unroll
    for (int kb = 0; kb < 16; ++kb) {
        __syncthreads();                       // drains glds(kb) + aload(kb)
        {
            uint4 aw;
            aw.x = cvt2(a0.x, a0.y);  aw.y = cvt2(a0.z, a0.w);
            aw.z = cvt2(a1.x, a1.y);  aw.w = cvt2(a1.z, a1.w);
            *reinterpret_cast<uint4*>(&As[arow * LDA + akq * 8]) = aw;
        }
        __syncthreads();                       // As(kb) + Bs[kb&1] visible

        if (kb < 15) {                         // next stages fly across MFMA
            const char* src = wsrc + (size_t)(kb + 1) * 32768;
            #pragma unroll
            for (int q = 0; q < 4; ++q)
                gload_lds16(src + (q * 256 + t) * 16,
                            (char*)&Bs[(kb + 1) & 1][0] + (q * 256 + t) * 16);
            a0 = *reinterpret_cast<const float4*>(aptr + (kb + 1) * 32);
            a1 = *reinterpret_cast<const float4*>(aptr + (kb + 1) * 32 + 4);
        }

        const ushort* Bp = (kb & 1) ? Bp1 : Bp0;
        bf16x8 af[4], bfr[4];
        #pragma unroll
        for (int m = 0; m < 4; ++m)
            af[m] = *reinterpret_cast<const bf16x8*>(Ap + m * 640);
        #pragma unroll
        for (int n = 0; n < 4; ++n)
            bfr[n] = *reinterpret_cast<const bf16x8*>(Bp + n * 512);
        #pragma unroll
        for (int m = 0; m < 4; ++m)
            #pragma unroll
            for (int n = 0; n < 4; ++n)
                acc[m][n] = __builtin_amdgcn_mfma_f32_16x16x32_bf16(
                    af[m], bfr[n], acc[m][n], 0, 0, 0);
    }

    // epilogue: partial energy over this block's 256 g
    float dpv[4], vv[4];
    #pragma unroll
    for (int n = 0; n < 4; ++n) {
        const int g = gh * 256 + wv * 64 + n * 16 + gl;
        dpv[n] = dp[b * HID + g];
        vv[n]  = v[g];
    }
    float p[4][4];
    #pragma unroll
    for (int m = 0; m < 4; ++m)
        #pragma unroll
        for (int r = 0; r < 4; ++r) p[m][r] = 0.f;
    #pragma unroll
    for (int n = 0; n < 4; ++n)
        #pragma unroll
        for (int m = 0; m < 4; ++m)
            #pragma unroll
            for (int r = 0; r < 4; ++r)
                p[m][r] += fast_tanh(dpv[n] + acc[m][n][r]) * vv[n];

    #pragma unroll
    for (int m = 0; m < 4; ++m)
        #pragma unroll
        for (int r = 0; r < 4; ++r) {
            float x = p[m][r];
            x += __shfl_xor(x, 1);
            x += __shfl_xor(x, 2);
            x += __shfl_xor(x, 4);
            x += __shfl_xor(x, 8);
            p[m][r] = x;
        }
    if (gl == 0) {
        #pragma unroll
        for (int m = 0; m < 4; ++m)
            #pragma unroll
            for (int r = 0; r < 4; ++r)
                part[wv][m * 16 + rg * 4 + r] = p[m][r];
    }
    __syncthreads();

    if (t < 64) {
        const float e = part[0][t] + part[1][t] + part[2][t] + part[3][t];
        eparts[(size_t)gh * BATCH * SEQ + (size_t)b * SEQ + s0 + t] = e;
    }
}

// ---------------------------------------------------------------------------
// K3: softmax over s per b; sums the two g-half partials, writes attn.
// ---------------------------------------------------------------------------
__global__ void k_softmax(const float* __restrict__ eparts,
                          float* __restrict__ attn)
{
    __shared__ float redm[4], reds[4];
    const int b = blockIdx.x, t = threadIdx.x;
    const float* e0 = eparts + (size_t)b * SEQ;
    const float* e1 = eparts + (size_t)BATCH * SEQ + (size_t)b * SEQ;

    float4 ev[4];
    float m = -3.4e38f;
    #pragma unroll
    for (int i = 0; i < 4; ++i) {
        const float4 x = *reinterpret_cast<const float4*>(e0 + i * 1024 + t * 4);
        const float4 y = *reinterpret_cast<const float4*>(e1 + i * 1024 + t * 4);
        ev[i] = make_float4(x.x + y.x, x.y + y.y, x.z + y.z, x.w + y.w);
        m = fmaxf(m, fmaxf(fmaxf(ev[i].x, ev[i].y), fmaxf(ev[i].z, ev[i].w)));
    }
    #pragma unroll
    for (int off = 1; off < 64; off <<= 1) m = fmaxf(m, __shfl_xor(m, off));
    if ((t & 63) == 0) redm[t >> 6] = m;
    __syncthreads();
    m = fmaxf(fmaxf(redm[0], redm[1]), fmaxf(redm[2], redm[3]));

    float s = 0.f;
    #pragma unroll
    for (int i = 0; i < 4; ++i) {
        ev[i].x = __expf(ev[i].x - m);  ev[i].y = __expf(ev[i].y - m);
        ev[i].z = __expf(ev[i].z - m);  ev[i].w = __expf(ev[i].w - m);
        s += (ev[i].x + ev[i].y) + (ev[i].z + ev[i].w);
    }
    #pragma unroll
    for (int off = 1; off < 64; off <<= 1) s += __shfl_xor(s, off);
    if ((t & 63) == 0) reds[t >> 6] = s;
    __syncthreads();
    s = (reds[0] + reds[1]) + (reds[2] + reds[3]);
    const float inv = 1.0f / s;

    float* o = attn + (size_t)b * SEQ;
    #pragma unroll
    for (int i = 0; i < 4; ++i) {
        const float4 w4 = make_float4(ev[i].x * inv, ev[i].y * inv,
                                      ev[i].z * inv, ev[i].w * inv);
        *reinterpret_cast<float4*>(o + i * 1024 + t * 4) = w4;
    }
}

// ---------------------------------------------------------------------------
// K4: partial context. grid = (64 b, 16 s-splits), 256 threads.
// ---------------------------------------------------------------------------
__global__ void k_ctxpart(const float* __restrict__ enc,
                          const float* __restrict__ attn,
                          float* __restrict__ pctx)
{
    __shared__ float w[256];
    const int b  = blockIdx.x;
    const int sp = blockIdx.y;
    const int t  = threadIdx.x;

    w[t] = attn[(size_t)b * SEQ + sp * 256 + t];
    __syncthreads();

    const float2* e2 = reinterpret_cast<const float2*>(enc);
    size_t idx = ((size_t)sp * 256 * BATCH + b) * (HID / 2) + t;
    const size_t stride = (size_t)BATCH * (HID / 2);

    float ax = 0.f, ay = 0.f;
    #pragma unroll 4
    for (int s = 0; s < 256; ++s) {
        const float2 ev = e2[idx];
        const float ws = w[s];
        ax = fmaf(ws, ev.x, ax);
        ay = fmaf(ws, ev.y, ay);
        idx += stride;
    }
    float2* p2 = reinterpret_cast<float2*>(pctx);
    p2[((size_t)sp * BATCH + b) * (HID / 2) + t] = make_float2(ax, ay);
}

// ---------------------------------------------------------------------------
// K5: context[b][h] = sum over 16 splits.
// ---------------------------------------------------------------------------
__global__ void k_ctxsum(const float* __restrict__ pctx,
                         float* __restrict__ ctx)
{
    const int i = blockIdx.x * 256 + threadIdx.x;
    float s = 0.f;
    #pragma unroll
    for (int sp = 0; sp < 16; ++sp) s += pctx[(size_t)sp * BATCH * HID + i];
    ctx[i] = s;
}

// ---------------------------------------------------------------------------
extern "C" void kernel_launch(void* const* d_in, const int* in_sizes, int n_in,
                              void* d_out, int out_size, void* d_ws, size_t ws_size,
                              hipStream_t stream)
{
    const float* dh  = (const float*)d_in[0];
    const float* enc = (const float*)d_in[1];
    const float* W1  = (const float*)d_in[2];
    const float* W2  = (const float*)d_in[3];
    const float* v   = (const float*)d_in[4];

    float* out  = (float*)d_out;
    float* ctx  = out;                           // 64*512
    float* attn = out + BATCH * HID;             // 64*4096

    float*  dp      = (float*)d_ws;                  // 128 KiB
    ushort* W2t     = (ushort*)(dp + BATCH * HID);   // 512 KiB
    float*  shared2 = (float*)(W2t + HID * HID);     // 2 MiB, dual-use:
    float*  eparts  = shared2;                       //   [2][B][S] until softmax
    float*  pctx    = shared2;                       //   [16][B][H] after

    k_cvtW2  <<<128, 256, 0, stream>>>(W2, W2t);
    k_decproj<<<HID, 256, 0, stream>>>(dh, W1, dp);
    k_energy <<<8192, 256, 0, stream>>>(enc, W2t, dp, v, eparts);
    k_softmax<<<BATCH, 256, 0, stream>>>(eparts, attn);
    k_ctxpart<<<dim3(BATCH, 16), 256, 0, stream>>>(enc, attn, pctx);
    k_ctxsum <<<BATCH * HID / 256, 256, 0, stream>>>(pctx, ctx);
}

// Round 7
// 327.976 us; speedup vs baseline: 1.2649x; 1.0419x over previous
//
#include <hip/hip_runtime.h>
#include <math.h>

// Bahdanau attention, round 6: B via direct fragment-order global loads.
// W2t is pre-arranged so each lane's MFMA B-fragment is one coalesced 16B
// load from L2 -> no B staging in LDS, no B barriers. LDS only stages the
// 4KB A tile (double-buffered, one barrier/step).
//   ws: dp | W2t (fragment order) | shared2 (eparts then pctx) = 2.625 MiB

#define BATCH 64
#define SEQ   4096
#define HID   512

typedef __attribute__((ext_vector_type(8))) short bf16x8;
typedef __attribute__((ext_vector_type(4))) float f32x4;

__device__ __forceinline__ float fast_tanh(float x) {
    return 1.0f - 2.0f / (__expf(2.0f * x) + 1.0f);
}

__device__ __forceinline__ unsigned cvt2(float lo, float hi) {
    unsigned r;
    asm("v_cvt_pk_bf16_f32 %0, %1, %2" : "=v"(r) : "v"(lo), "v"(hi));
    return r;
}

// ---------------------------------------------------------------------------
// K0: W2 fp32 -> bf16 in MFMA fragment order:
//   W2t[((gh*16 + kb)*4 + wv)*4 + n][lane][j]  (512 u16 per fragment)
// holds W2[g][k] with g = gh*256 + wv*64 + n*16 + (lane&15),
//                     k = kb*32 + (lane>>4)*8 + j.
// Thread n: g = n>>6, kc = n&63 -> (kb = kc>>2, rgl = kc&3), 8 k's.
// ---------------------------------------------------------------------------
__global__ void k_cvtW2(const float* __restrict__ W2, ushort* __restrict__ W2t)
{
    const int n  = blockIdx.x * 256 + threadIdx.x;   // 0..32767
    const int g  = n >> 6, kc = n & 63;
    const int kb = kc >> 2, rgl = kc & 3;
    const int gh = g >> 8, wv = (g >> 6) & 3, fn = (g >> 4) & 3, gl = g & 15;

    const float* src = W2 + (size_t)g * HID + kc * 8;
    const float4 x = *reinterpret_cast<const float4*>(src);
    const float4 y = *reinterpret_cast<const float4*>(src + 4);
    uint4 u;
    u.x = cvt2(x.x, x.y);  u.y = cvt2(x.z, x.w);
    u.z = cvt2(y.x, y.y);  u.w = cvt2(y.z, y.w);

    const size_t dst = (size_t)gh * 131072 + kb * 8192 + wv * 2048 + fn * 512
                     + (rgl * 16 + gl) * 8;
    *reinterpret_cast<uint4*>(W2t + dst) = u;
}

// ---------------------------------------------------------------------------
// K1: dp[b][g] = sum_h dh[b][h] * W1[g][h]  (fp32, tiny)
// ---------------------------------------------------------------------------
__global__ void k_decproj(const float* __restrict__ dh,
                          const float* __restrict__ W1,
                          float* __restrict__ dp)
{
    __shared__ float wrow[HID];
    const int g = blockIdx.x;
    const int t = threadIdx.x;
    for (int i = t; i < HID; i += 256) wrow[i] = W1[g * HID + i];
    __syncthreads();

    const int b = t >> 2, q = t & 3;
    const float* dhb = dh + b * HID + q * 128;
    const float* wr  = wrow + q * 128;
    float acc = 0.f;
    #pragma unroll 8
    for (int i = 0; i < 128; i += 4) {
        const float4 d4 = *reinterpret_cast<const float4*>(dhb + i);
        acc = fmaf(d4.x, wr[i + 0], acc);
        acc = fmaf(d4.y, wr[i + 1], acc);
        acc = fmaf(d4.z, wr[i + 2], acc);
        acc = fmaf(d4.w, wr[i + 3], acc);
    }
    acc += __shfl_xor(acc, 1);
    acc += __shfl_xor(acc, 2);
    if (q == 0) dp[b * HID + g] = acc;
}

// ---------------------------------------------------------------------------
// K2: energy partial GEMM. grid = 8192 blocks, 256 thr (4 waves).
// Sibling g-halves of one (s-chunk, b) at blockIdx distance 8 -> same XCD.
// Block tile 64s x 256g, BK=32, 16 K-steps. Wave wv: g [gh*256+wv*64, +64).
// A: global->reg (2-deep prefetch) -> cvt_pk -> As[2] (LDA=40) -> ds_read.
// B: direct 16B fragment loads from W2t (L2-resident), no LDS.
// One __syncthreads per K-step.
// ---------------------------------------------------------------------------
#define LDA 40

__global__ __launch_bounds__(256, 4)
void k_energy(const float* __restrict__ enc, const ushort* __restrict__ W2t,
              const float* __restrict__ dp,  const float* __restrict__ v,
              float* __restrict__ eparts)
{
    __shared__ __align__(16) ushort As[2][64 * LDA];   // 2 x 5 KiB
    __shared__ float part[4][64];                      // 1 KiB

    // block decode: idx -> (gh, schunk, b); siblings (gh=0/1) 8 apart.
    const int idx  = blockIdx.x;
    const int g16  = idx >> 4, rr = idx & 15;
    const int gh   = rr >> 3;
    const int pair = (g16 << 3) | (rr & 7);    // 0..4095
    const int schunk = pair & 63;
    const int b      = pair >> 6;
    const int s0     = schunk * 64;

    const int t    = threadIdx.x;
    const int lane = t & 63;
    const int wv   = t >> 6;                   // wave = N-block 0..3
    const int gl   = lane & 15, rg = lane >> 4;

    f32x4 acc[4][4];
    const f32x4 z = {0.f, 0.f, 0.f, 0.f};
    #pragma unroll
    for (int m = 0; m < 4; ++m)
        #pragma unroll
        for (int n = 0; n < 4; ++n) acc[m][n] = z;

    // A staging: thread -> (row = t>>2 in [0,64), kq = t&3), 8 floats/step
    const int arow = t >> 2, akq = t & 3;
    const float* aptr = enc + ((size_t)(s0 + arow) * BATCH + b) * HID + akq * 8;
    ushort* Aw0 = &As[0][arow * LDA + akq * 8];
    ushort* Aw1 = &As[1][arow * LDA + akq * 8];

    // A fragment read bases (per lane), one per buffer
    const ushort* Ap0 = &As[0][gl * LDA + rg * 8];
    const ushort* Ap1 = &As[1][gl * LDA + rg * 8];

    // B fragment base: W2t + gh*131072 + wv*2048 + lane*8; step kb at +kb*8192,
    // frag n at +n*512 (u16 units)
    const ushort* bptr = W2t + (size_t)gh * 131072 + wv * 2048 + lane * 8;

    // prologue: stage A(0), prefetch A(1)
    float4 a0 = *reinterpret_cast<const float4*>(aptr);
    float4 a1 = *reinterpret_cast<const float4*>(aptr + 4);
    {
        uint4 aw;
        aw.x = cvt2(a0.x, a0.y);  aw.y = cvt2(a0.z, a0.w);
        aw.z = cvt2(a1.x, a1.y);  aw.w = cvt2(a1.z, a1.w);
        *reinterpret_cast<uint4*>(Aw0) = aw;
    }
    a0 = *reinterpret_cast<const float4*>(aptr + 32);
    a1 = *reinterpret_cast<const float4*>(aptr + 36);
    __syncthreads();

    #pragma unroll
    for (int kb = 0; kb < 16; ++kb) {
        // B fragments for this step: 4 coalesced 16B loads from L2
        bf16x8 bfr[4];
        #pragma unroll
        for (int n = 0; n < 4; ++n)
            bfr[n] = *reinterpret_cast<const bf16x8*>(bptr + kb * 8192 + n * 512);

        // A fragments from current buffer
        const ushort* Ap = (kb & 1) ? Ap1 : Ap0;
        bf16x8 af[4];
        #pragma unroll
        for (int m = 0; m < 4; ++m)
            af[m] = *reinterpret_cast<const bf16x8*>(Ap + m * 16 * LDA);

        // stage A(kb+1) into other buffer; prefetch A(kb+2)
        if (kb < 15) {
            uint4 aw;
            aw.x = cvt2(a0.x, a0.y);  aw.y = cvt2(a0.z, a0.w);
            aw.z = cvt2(a1.x, a1.y);  aw.w = cvt2(a1.z, a1.w);
            *reinterpret_cast<uint4*>((kb & 1) ? Aw0 : Aw1) = aw;
        }
        if (kb < 14) {
            a0 = *reinterpret_cast<const float4*>(aptr + (kb + 2) * 32);
            a1 = *reinterpret_cast<const float4*>(aptr + (kb + 2) * 32 + 4);
        }

        #pragma unroll
        for (int m = 0; m < 4; ++m)
            #pragma unroll
            for (int n = 0; n < 4; ++n)
                acc[m][n] = __builtin_amdgcn_mfma_f32_16x16x32_bf16(
                    af[m], bfr[n], acc[m][n], 0, 0, 0);

        __syncthreads();
    }

    // epilogue: partial energy over this block's 256 g
    float dpv[4], vv[4];
    #pragma unroll
    for (int n = 0; n < 4; ++n) {
        const int g = gh * 256 + wv * 64 + n * 16 + gl;
        dpv[n] = dp[b * HID + g];
        vv[n]  = v[g];
    }
    float p[4][4];
    #pragma unroll
    for (int m = 0; m < 4; ++m)
        #pragma unroll
        for (int r = 0; r < 4; ++r) p[m][r] = 0.f;
    #pragma unroll
    for (int n = 0; n < 4; ++n)
        #pragma unroll
        for (int m = 0; m < 4; ++m)
            #pragma unroll
            for (int r = 0; r < 4; ++r)
                p[m][r] += fast_tanh(dpv[n] + acc[m][n][r]) * vv[n];

    #pragma unroll
    for (int m = 0; m < 4; ++m)
        #pragma unroll
        for (int r = 0; r < 4; ++r) {
            float x = p[m][r];
            x += __shfl_xor(x, 1);
            x += __shfl_xor(x, 2);
            x += __shfl_xor(x, 4);
            x += __shfl_xor(x, 8);
            p[m][r] = x;
        }
    if (gl == 0) {
        #pragma unroll
        for (int m = 0; m < 4; ++m)
            #pragma unroll
            for (int r = 0; r < 4; ++r)
                part[wv][m * 16 + rg * 4 + r] = p[m][r];
    }
    __syncthreads();

    if (t < 64) {
        const float e = part[0][t] + part[1][t] + part[2][t] + part[3][t];
        eparts[(size_t)gh * BATCH * SEQ + (size_t)b * SEQ + s0 + t] = e;
    }
}

// ---------------------------------------------------------------------------
// K3: softmax over s per b; sums the two g-half partials, writes attn.
// ---------------------------------------------------------------------------
__global__ void k_softmax(const float* __restrict__ eparts,
                          float* __restrict__ attn)
{
    __shared__ float redm[4], reds[4];
    const int b = blockIdx.x, t = threadIdx.x;
    const float* e0 = eparts + (size_t)b * SEQ;
    const float* e1 = eparts + (size_t)BATCH * SEQ + (size_t)b * SEQ;

    float4 ev[4];
    float m = -3.4e38f;
    #pragma unroll
    for (int i = 0; i < 4; ++i) {
        const float4 x = *reinterpret_cast<const float4*>(e0 + i * 1024 + t * 4);
        const float4 y = *reinterpret_cast<const float4*>(e1 + i * 1024 + t * 4);
        ev[i] = make_float4(x.x + y.x, x.y + y.y, x.z + y.z, x.w + y.w);
        m = fmaxf(m, fmaxf(fmaxf(ev[i].x, ev[i].y), fmaxf(ev[i].z, ev[i].w)));
    }
    #pragma unroll
    for (int off = 1; off < 64; off <<= 1) m = fmaxf(m, __shfl_xor(m, off));
    if ((t & 63) == 0) redm[t >> 6] = m;
    __syncthreads();
    m = fmaxf(fmaxf(redm[0], redm[1]), fmaxf(redm[2], redm[3]));

    float s = 0.f;
    #pragma unroll
    for (int i = 0; i < 4; ++i) {
        ev[i].x = __expf(ev[i].x - m);  ev[i].y = __expf(ev[i].y - m);
        ev[i].z = __expf(ev[i].z - m);  ev[i].w = __expf(ev[i].w - m);
        s += (ev[i].x + ev[i].y) + (ev[i].z + ev[i].w);
    }
    #pragma unroll
    for (int off = 1; off < 64; off <<= 1) s += __shfl_xor(s, off);
    if ((t & 63) == 0) reds[t >> 6] = s;
    __syncthreads();
    s = (reds[0] + reds[1]) + (reds[2] + reds[3]);
    const float inv = 1.0f / s;

    float* o = attn + (size_t)b * SEQ;
    #pragma unroll
    for (int i = 0; i < 4; ++i) {
        const float4 w4 = make_float4(ev[i].x * inv, ev[i].y * inv,
                                      ev[i].z * inv, ev[i].w * inv);
        *reinterpret_cast<float4*>(o + i * 1024 + t * 4) = w4;
    }
}

// ---------------------------------------------------------------------------
// K4: partial context. grid = (64 b, 16 s-splits), 256 threads.
// ---------------------------------------------------------------------------
__global__ void k_ctxpart(const float* __restrict__ enc,
                          const float* __restrict__ attn,
                          float* __restrict__ pctx)
{
    __shared__ float w[256];
    const int b  = blockIdx.x;
    const int sp = blockIdx.y;
    const int t  = threadIdx.x;

    w[t] = attn[(size_t)b * SEQ + sp * 256 + t];
    __syncthreads();

    const float2* e2 = reinterpret_cast<const float2*>(enc);
    size_t idx = ((size_t)sp * 256 * BATCH + b) * (HID / 2) + t;
    const size_t stride = (size_t)BATCH * (HID / 2);

    float ax = 0.f, ay = 0.f;
    #pragma unroll 4
    for (int s = 0; s < 256; ++s) {
        const float2 ev = e2[idx];
        const float ws = w[s];
        ax = fmaf(ws, ev.x, ax);
        ay = fmaf(ws, ev.y, ay);
        idx += stride;
    }
    float2* p2 = reinterpret_cast<float2*>(pctx);
    p2[((size_t)sp * BATCH + b) * (HID / 2) + t] = make_float2(ax, ay);
}

// ---------------------------------------------------------------------------
// K5: context[b][h] = sum over 16 splits.
// ---------------------------------------------------------------------------
__global__ void k_ctxsum(const float* __restrict__ pctx,
                         float* __restrict__ ctx)
{
    const int i = blockIdx.x * 256 + threadIdx.x;
    float s = 0.f;
    #pragma unroll
    for (int sp = 0; sp < 16; ++sp) s += pctx[(size_t)sp * BATCH * HID + i];
    ctx[i] = s;
}

// ---------------------------------------------------------------------------
extern "C" void kernel_launch(void* const* d_in, const int* in_sizes, int n_in,
                              void* d_out, int out_size, void* d_ws, size_t ws_size,
                              hipStream_t stream)
{
    const float* dh  = (const float*)d_in[0];
    const float* enc = (const float*)d_in[1];
    const float* W1  = (const float*)d_in[2];
    const float* W2  = (const float*)d_in[3];
    const float* v   = (const float*)d_in[4];

    float* out  = (float*)d_out;
    float* ctx  = out;                           // 64*512
    float* attn = out + BATCH * HID;             // 64*4096

    float*  dp      = (float*)d_ws;                  // 128 KiB
    ushort* W2t     = (ushort*)(dp + BATCH * HID);   // 512 KiB (fragment order)
    float*  shared2 = (float*)(W2t + HID * HID);     // 2 MiB, dual-use:
    float*  eparts  = shared2;                       //   [2][B][S] until softmax
    float*  pctx    = shared2;                       //   [16][B][H] after

    k_cvtW2  <<<128, 256, 0, stream>>>(W2, W2t);
    k_decproj<<<HID, 256, 0, stream>>>(dh, W1, dp);
    k_energy <<<8192, 256, 0, stream>>>(enc, W2t, dp, v, eparts);
    k_softmax<<<BATCH, 256, 0, stream>>>(eparts, attn);
    k_ctxpart<<<dim3(BATCH, 16), 256, 0, stream>>>(enc, attn, pctx);
    k_ctxsum <<<BATCH * HID / 256, 256, 0, stream>>>(pctx, ctx);
}